// Round 1
// baseline (978.036 us; speedup 1.0000x reference)
//
#include <hip/hip_runtime.h>
#include <hip/hip_bf16.h>
#include <math.h>

#define T_TOK 8192
#define D_MODEL 2048
#define N_EXP 16
#define CAP 512

// ws layout:
// [0, 64KB)            : pref64   (unsigned long long[T_TOK])   sorted expert prefs, top nibble = best
// [64KB, 576KB)        : probs    (float[T_TOK][N_EXP])         softmax probabilities
// [576KB, 608KB)       : tok2exp  (int[T_TOK])                  assigned expert per token

__device__ __forceinline__ unsigned int f2ord(float f) {
    // monotone map f32 -> u32 (order-preserving for finite floats)
    unsigned int b = __float_as_uint(f);
    return (b & 0x80000000u) ? ~b : (b | 0x80000000u);
}

// ---------------- Kernel A: affinities + softmax probs + preference lists ----------------
__global__ __launch_bounds__(256) void affinity_kernel(
    const float* __restrict__ feat, const float* __restrict__ W,
    const float* __restrict__ bias,
    unsigned long long* __restrict__ pref, float* __restrict__ probs)
{
    __shared__ float f_lds[16][132];   // 16 tokens x 128 k, padded
    __shared__ float w_lds[16][132];   // 16 experts x 128 k, padded
    __shared__ float aff_lds[16][16];  // [token][expert]
    __shared__ float m_lds[16], s_lds[16];

    const int tid = threadIdx.x;
    const int e   = tid & 15;          // expert for compute
    const int tau = tid >> 4;          // token (0..15) for compute AND load row
    const int t0  = blockIdx.x * 16;

    const int ldr_row = tid >> 4;         // row 0..15
    const int ldr_off = (tid & 15) * 8;   // 8 consecutive floats

    float acc = 0.f;

    for (int kc = 0; kc < D_MODEL; kc += 128) {
        __syncthreads();
        const float4* fs = (const float4*)(feat + (size_t)(t0 + ldr_row) * D_MODEL + kc + ldr_off);
        float4 fa = fs[0], fb = fs[1];
        const float4* wsrc = (const float4*)(W + (size_t)ldr_row * D_MODEL + kc + ldr_off);
        float4 wa = wsrc[0], wb = wsrc[1];
        *(float4*)&f_lds[ldr_row][ldr_off]     = fa;
        *(float4*)&f_lds[ldr_row][ldr_off + 4] = fb;
        *(float4*)&w_lds[ldr_row][ldr_off]     = wa;
        *(float4*)&w_lds[ldr_row][ldr_off + 4] = wb;
        __syncthreads();
        #pragma unroll
        for (int k = 0; k < 128; k += 4) {
            float4 fv = *(const float4*)&f_lds[tau][k];
            float4 wv = *(const float4*)&w_lds[e][k];
            acc += fv.x * wv.x;
            acc += fv.y * wv.y;
            acc += fv.z * wv.z;
            acc += fv.w * wv.w;
        }
    }

    float aff = acc + bias[e];
    aff_lds[tau][e] = aff;
    __syncthreads();

    if (tid < 16) {
        const int t = tid;
        float m = -INFINITY;
        #pragma unroll
        for (int j = 0; j < 16; j++) m = fmaxf(m, aff_lds[t][j]);
        float s = 0.f;
        #pragma unroll
        for (int j = 0; j < 16; j++) s += __expf(aff_lds[t][j] - m);
        m_lds[t] = m;
        s_lds[t] = s;

        // build descending preference list; ties -> lower expert index first
        unsigned long long key[16];
        #pragma unroll
        for (int j = 0; j < 16; j++) {
            key[j] = ((unsigned long long)f2ord(aff_lds[t][j]) << 4) |
                     (unsigned long long)(15 - j);
        }
        unsigned long long p = 0ull;
        unsigned int used = 0;
        for (int r = 0; r < 16; r++) {
            unsigned long long bk = 0ull;
            int be = 0;
            for (int j = 0; j < 16; j++) {
                if (!((used >> j) & 1u) && key[j] > bk) { bk = key[j]; be = j; }
            }
            used |= (1u << be);
            p = (p << 4) | (unsigned long long)be;
        }
        pref[t0 + t] = p;  // top nibble (bits 60..63) = most preferred expert
    }
    __syncthreads();

    const float pm = m_lds[tau];
    const float ps = s_lds[tau];
    probs[(size_t)(t0 + tau) * N_EXP + e] = __expf(aff_lds[tau][e] - pm) / ps;
}

// ---------------- Kernel B: sequential balanced assignment (one wave) ----------------
__global__ __launch_bounds__(64) void assign_kernel(
    const unsigned long long* __restrict__ pref,
    float* __restrict__ out0, int* __restrict__ tok2exp)
{
    const int lane = threadIdx.x;
    int cap  = (lane < N_EXP) ? CAP : 0;  // lane e holds expert e's remaining capacity
    int fill = 0;                         // lane e holds expert e's assigned count
    unsigned int avail = 0xFFFFu;         // wave-uniform: experts with capacity

    for (int b = 0; b < T_TOK / 64; b++) {
        // cooperative batch prefetch: lane i holds token (b*64+i)'s pref list
        unsigned long long p = pref[b * 64 + lane];
        unsigned int lo = (unsigned int)p;
        unsigned int hi = (unsigned int)(p >> 32);

        for (int i = 0; i < 64; i++) {
            unsigned int plo = (unsigned int)__builtin_amdgcn_readlane((int)lo, i);
            unsigned int phi = (unsigned int)__builtin_amdgcn_readlane((int)hi, i);
            unsigned long long pp = ((unsigned long long)phi << 32) | (unsigned long long)plo;

            // walk preference nibbles until an available expert is found
            int e;
            for (;;) {
                e = (int)(pp >> 60);
                if ((avail >> e) & 1u) break;
                pp <<= 4;
            }

            const int t = b * 64 + i;
            if (lane == e) {
                out0[e * CAP + fill] = (float)t;  // sort_by_expert[pos] = t
                tok2exp[t] = e;
                fill++;
                cap--;
            }
            // wave-uniform capacity check (readlane ignores exec mask)
            int c = __builtin_amdgcn_readlane(cap, e);
            if (c == 0) avail &= ~(1u << e);
        }
    }
}

// ---------------- Kernel C: gather routing probs for assigned experts ----------------
__global__ __launch_bounds__(256) void gather_kernel(
    const float* __restrict__ probs, const int* __restrict__ tok2exp,
    float* __restrict__ out1)
{
    const int t = blockIdx.x * 256 + threadIdx.x;
    if (t < T_TOK) {
        out1[t] = probs[(size_t)t * N_EXP + tok2exp[t]];
    }
}

extern "C" void kernel_launch(void* const* d_in, const int* in_sizes, int n_in,
                              void* d_out, int out_size, void* d_ws, size_t ws_size,
                              hipStream_t stream) {
    const float* feat = (const float*)d_in[0];
    const float* W    = (const float*)d_in[1];
    const float* bias = (const float*)d_in[2];
    // d_in[3] = is_training: unused (output identical either way)

    float* out = (float*)d_out;
    char*  ws  = (char*)d_ws;

    unsigned long long* pref = (unsigned long long*)ws;                       // 64 KB
    float* probs             = (float*)(ws + 65536);                          // 512 KB
    int*   tok2exp           = (int*)(ws + 65536 + (size_t)T_TOK * N_EXP * 4); // 32 KB

    hipLaunchKernelGGL(affinity_kernel, dim3(T_TOK / 16), dim3(256), 0, stream,
                       feat, W, bias, pref, probs);
    hipLaunchKernelGGL(assign_kernel, dim3(1), dim3(64), 0, stream,
                       pref, out, tok2exp);
    hipLaunchKernelGGL(gather_kernel, dim3(T_TOK / 256), dim3(256), 0, stream,
                       probs, tok2exp, out + T_TOK);
}

// Round 2
// 305.320 us; speedup vs baseline: 3.2033x; 3.2033x over previous
//
#include <hip/hip_runtime.h>
#include <hip/hip_bf16.h>
#include <math.h>

#define T_TOK 8192
#define D_MODEL 2048
#define N_EXP 16
#define CAP 512
#define KSPLIT 4
#define KRANGE (D_MODEL / KSPLIT)   // 512
#define TTILE 128
#define KCHUNK 32
#define NSEG (T_TOK / 64)           // 128

// ws layout:
// [0, 2MB)        : partial  float[KSPLIT][T_TOK][N_EXP]
// [2MB, 2MB+64KB) : pref64   u64[T_TOK]  (sorted expert prefs, top nibble = best)
// [+64KB, +576KB) : probs    float[T_TOK][N_EXP]

__device__ __forceinline__ unsigned int f2ord(float f) {
    unsigned int b = __float_as_uint(f);
    return (b & 0x80000000u) ? ~b : (b | 0x80000000u);
}

// ---------------- Kernel A1: K-split partial GEMM (feat @ W^T) ----------------
__global__ __launch_bounds__(256) void gemm_partial_kernel(
    const float* __restrict__ feat, const float* __restrict__ W,
    float* __restrict__ partial)
{
    __shared__ float f_lds[TTILE][32];   // XOR-swizzled, row stride 32 floats
    __shared__ float w_lds[N_EXP][36];

    const int tid = threadIdx.x;
    const int t0  = blockIdx.x * TTILE;
    const int ks  = blockIdx.y;
    const int k0  = ks * KRANGE;

    const int tg = tid >> 3;   // 0..31: token group (4 tokens)
    const int eg = tid & 7;    // 0..7 : expert group (2 experts)

    float acc[4][2] = {{0.f,0.f},{0.f,0.f},{0.f,0.f},{0.f,0.f}};

    const int l_tok = tid >> 3;  // loader row base
    const int l_kg  = tid & 7;   // loader k-group

    for (int kc = 0; kc < KRANGE; kc += KCHUNK) {
        __syncthreads();
        #pragma unroll
        for (int it = 0; it < 4; ++it) {
            int row = l_tok + it * 32;
            float4 v = *(const float4*)(feat + (size_t)(t0 + row) * D_MODEL + k0 + kc + l_kg * 4);
            int sw = (l_kg ^ ((row >> 2) & 7)) * 4;
            *(float4*)&f_lds[row][sw] = v;
        }
        if (tid < 128) {
            int e = tid >> 3, kg = tid & 7;
            float4 v = *(const float4*)(W + (size_t)e * D_MODEL + k0 + kc + kg * 4);
            *(float4*)&w_lds[e][kg * 4] = v;
        }
        __syncthreads();
        #pragma unroll
        for (int kg = 0; kg < 8; ++kg) {
            int sw = (kg ^ (tg & 7)) * 4;   // (row>>2)&7 == tg&7 for all 4 rows
            float4 fv[4], wv[2];
            #pragma unroll
            for (int i = 0; i < 4; ++i)
                fv[i] = *(const float4*)&f_lds[tg * 4 + i][sw];
            #pragma unroll
            for (int j = 0; j < 2; ++j)
                wv[j] = *(const float4*)&w_lds[eg * 2 + j][kg * 4];
            #pragma unroll
            for (int i = 0; i < 4; ++i)
                #pragma unroll
                for (int j = 0; j < 2; ++j) {
                    acc[i][j] += fv[i].x * wv[j].x;
                    acc[i][j] += fv[i].y * wv[j].y;
                    acc[i][j] += fv[i].z * wv[j].z;
                    acc[i][j] += fv[i].w * wv[j].w;
                }
        }
    }
    #pragma unroll
    for (int i = 0; i < 4; ++i) {
        int t = t0 + tg * 4 + i;
        float2 v = make_float2(acc[i][0], acc[i][1]);
        *(float2*)(partial + ((size_t)ks * T_TOK + t) * N_EXP + eg * 2) = v;
    }
}

// ---------------- Kernel A2: reduce partials + softmax + preference lists ----------------
__global__ __launch_bounds__(256) void finalize_kernel(
    const float* __restrict__ partial, const float* __restrict__ bias,
    unsigned long long* __restrict__ pref, float* __restrict__ probs)
{
    const int t = blockIdx.x * 256 + threadIdx.x;

    float aff[N_EXP];
    #pragma unroll
    for (int e = 0; e < N_EXP; ++e) aff[e] = 0.f;
    for (int ks = 0; ks < KSPLIT; ++ks) {
        const float4* p = (const float4*)(partial + ((size_t)ks * T_TOK + t) * N_EXP);
        #pragma unroll
        for (int q = 0; q < 4; ++q) {
            float4 v = p[q];
            aff[q*4+0] += v.x; aff[q*4+1] += v.y;
            aff[q*4+2] += v.z; aff[q*4+3] += v.w;
        }
    }
    #pragma unroll
    for (int e = 0; e < N_EXP; ++e) aff[e] += bias[e];

    float m = aff[0];
    #pragma unroll
    for (int e = 1; e < N_EXP; ++e) m = fmaxf(m, aff[e]);
    float s = 0.f;
    #pragma unroll
    for (int e = 0; e < N_EXP; ++e) s += __expf(aff[e] - m);

    float4* pr = (float4*)(probs + (size_t)t * N_EXP);
    #pragma unroll
    for (int q = 0; q < 4; ++q) {
        float4 v;
        v.x = __expf(aff[q*4+0] - m) / s;
        v.y = __expf(aff[q*4+1] - m) / s;
        v.z = __expf(aff[q*4+2] - m) / s;
        v.w = __expf(aff[q*4+3] - m) / s;
        pr[q] = v;
    }

    // descending preference list; ties -> lower expert index first
    unsigned long long key[N_EXP];
    #pragma unroll
    for (int j = 0; j < N_EXP; ++j)
        key[j] = ((unsigned long long)f2ord(aff[j]) << 4) | (unsigned long long)(15 - j);
    unsigned long long p = 0ull;
    unsigned int used = 0;
    for (int r = 0; r < N_EXP; ++r) {
        unsigned long long bk = 0ull; int be = 0;
        for (int j = 0; j < N_EXP; ++j)
            if (!((used >> j) & 1u) && key[j] > bk) { bk = key[j]; be = j; }
        used |= (1u << be);
        p = (p << 4) | (unsigned long long)be;
    }
    pref[t] = p;
}

// ---------------- Kernel B: round-based balanced assignment (1 block) ----------------
__global__ __launch_bounds__(1024) void assign_kernel(
    const unsigned long long* __restrict__ pref,
    const float* __restrict__ probs,
    float* __restrict__ out0, float* __restrict__ out1)
{
    __shared__ unsigned char  choice[T_TOK];
    __shared__ unsigned short cnt [NSEG][N_EXP];
    __shared__ unsigned short pseg[NSEG][N_EXP];
    __shared__ int rem_cap[N_EXP], cum_fill[N_EXP], fparr[N_EXP];
    __shared__ int s_avail, s_start, s_pmin, s_fe;

    const int tid  = threadIdx.x;
    const int wave = tid >> 6, lane = tid & 63;
    const unsigned long long lt_mask = (lane == 63) ? ~0ull >> 1 : ((1ull << (lane + 1)) - 1ull) >> 1;

    if (tid < N_EXP) { rem_cap[tid] = CAP; cum_fill[tid] = 0; }
    if (tid == 0) { s_avail = 0xFFFF; s_start = 0; }
    __syncthreads();

    for (int round = 0; round < N_EXP; ++round) {
        const int start = s_start;
        const unsigned int avail = (unsigned int)s_avail;

        // Phase 1: per-token choice = first available expert in pref order
        for (int t = start + tid; t < T_TOK; t += 1024) {
            unsigned long long pp = pref[t];
            int e = (int)(pp >> 60);
            while (!((avail >> e) & 1u)) { pp <<= 4; e = (int)(pp >> 60); }
            choice[t] = (unsigned char)e;
        }
        __syncthreads();

        // Phase 2: per-segment per-expert counts
        const int seg_lo = start >> 6;
        for (int s = seg_lo + wave; s < NSEG; s += 16) {
            int t = s * 64 + lane;
            int c = (t >= start) ? (int)choice[t] : -1;
            #pragma unroll
            for (int e = 0; e < N_EXP; ++e) {
                unsigned long long mm = __ballot(c == e);
                if (lane == e) cnt[s][e] = (unsigned short)__popcll(mm);
            }
        }
        __syncthreads();

        // Phase 3: sequential segment scan on lanes 0..15 -> fill position per expert
        if (tid < N_EXP) {
            const int e = tid;
            int fp = 0x7FFFFFFF;
            int cum = 0, fillseg = -1, k = 0;
            for (int s = seg_lo; s < NSEG; ++s) {
                pseg[s][e] = (unsigned short)cum;
                int c = cnt[s][e];
                if (fillseg < 0 && rem_cap[e] > 0 && cum + c >= rem_cap[e]) {
                    fillseg = s; k = rem_cap[e] - cum;
                }
                cum += c;
            }
            if (fillseg >= 0) {
                int need = k;
                for (int i = 0; i < 64; ++i) {
                    int t = fillseg * 64 + i;
                    if (t >= start && (int)choice[t] == e) {
                        if (--need == 0) { fp = t; break; }
                    }
                }
            }
            fparr[e] = fp;
        }
        __syncthreads();
        if (tid == 0) {
            int pm = 0x7FFFFFFF, fe = 0;
            for (int e = 0; e < N_EXP; ++e)
                if (fparr[e] < pm) { pm = fparr[e]; fe = e; }
            if (pm > T_TOK - 1) pm = T_TOK - 1;   // defensive; unreachable
            s_pmin = pm; s_fe = fe;
        }
        __syncthreads();
        const int pmin = s_pmin;
        const int segF = pmin >> 6;

        // Phase 4: finalize tokens [start, pmin] and write outputs
        for (int s = seg_lo + wave; s <= segF; s += 16) {
            int t = s * 64 + lane;
            bool valid = (t >= start && t <= pmin);
            int c = valid ? (int)choice[t] : -1;
            unsigned long long own = 0ull;
            #pragma unroll
            for (int e = 0; e < N_EXP; ++e) {
                unsigned long long mm = __ballot(c == e);
                if (c == e) own = mm;
            }
            if (valid) {
                int rank = (int)pseg[s][c] + (int)__popcll(own & lt_mask);
                int pos  = cum_fill[c] + rank;
                out0[c * CAP + pos] = (float)t;
                out1[t] = probs[(size_t)t * N_EXP + c];
            }
        }
        __syncthreads();

        // Phase 5: update per-expert state
        if (tid < N_EXP) {
            const int e = tid;
            int cF = 0;
            for (int i = 0; i < 64; ++i) {
                int t = segF * 64 + i;
                if (t >= start && t <= pmin && (int)choice[t] == e) cF++;
            }
            int fin = (int)pseg[segF][e] + cF;
            cum_fill[e] += fin;
            rem_cap[e]  -= fin;
        }
        __syncthreads();
        if (tid == 0) { s_avail &= ~(1 << s_fe); s_start = s_pmin + 1; }
        __syncthreads();
    }
}

extern "C" void kernel_launch(void* const* d_in, const int* in_sizes, int n_in,
                              void* d_out, int out_size, void* d_ws, size_t ws_size,
                              hipStream_t stream) {
    const float* feat = (const float*)d_in[0];
    const float* W    = (const float*)d_in[1];
    const float* bias = (const float*)d_in[2];

    float* out = (float*)d_out;
    char*  ws  = (char*)d_ws;

    float* partial = (float*)ws;                                   // 2 MB
    unsigned long long* pref = (unsigned long long*)(ws + (size_t)KSPLIT * T_TOK * N_EXP * 4);
    float* probs = (float*)((char*)pref + (size_t)T_TOK * 8);      // 512 KB

    hipLaunchKernelGGL(gemm_partial_kernel, dim3(T_TOK / TTILE, KSPLIT), dim3(256), 0, stream,
                       feat, W, partial);
    hipLaunchKernelGGL(finalize_kernel, dim3(T_TOK / 256), dim3(256), 0, stream,
                       partial, bias, pref, probs);
    hipLaunchKernelGGL(assign_kernel, dim3(1), dim3(1024), 0, stream,
                       pref, probs, out, out + T_TOK);
}

// Round 3
// 265.014 us; speedup vs baseline: 3.6905x; 1.1521x over previous
//
#include <hip/hip_runtime.h>
#include <hip/hip_bf16.h>
#include <math.h>

#define T_TOK 8192
#define D_MODEL 2048
#define N_EXP 16
#define CAP 512
#define TTILE 128
#define KCHUNK 32
#define NSEG (T_TOK / 64)           // 128

// ws layout:
// [0, ksplit*512KB)   : partial  float[ksplit][T_TOK][N_EXP]
// then                : pref64   u64[T_TOK]   (64 KB)
// then                : probs    float[T_TOK][N_EXP] (512 KB)

__device__ __forceinline__ unsigned int f2ord(float f) {
    unsigned int b = __float_as_uint(f);
    return (b & 0x80000000u) ? ~b : (b | 0x80000000u);
}

// ---------------- Kernel A1: K-split partial GEMM (feat @ W^T) ----------------
__global__ __launch_bounds__(256) void gemm_partial_kernel(
    const float* __restrict__ feat, const float* __restrict__ W,
    float* __restrict__ partial, int krange)
{
    __shared__ float f_lds[TTILE][32];   // XOR-swizzled, row stride 32 floats
    __shared__ float w_lds[N_EXP][36];

    const int tid = threadIdx.x;
    const int t0  = blockIdx.x * TTILE;
    const int ks  = blockIdx.y;
    const int k0  = ks * krange;

    const int tg = tid >> 3;   // 0..31: token group (4 tokens)
    const int eg = tid & 7;    // 0..7 : expert group (2 experts)

    float acc[4][2] = {{0.f,0.f},{0.f,0.f},{0.f,0.f},{0.f,0.f}};

    const int l_tok = tid >> 3;  // loader row base
    const int l_kg  = tid & 7;   // loader k-group

    float4 fA[4];
    float4 wA;

    // prefetch chunk 0
    #pragma unroll
    for (int it = 0; it < 4; ++it) {
        int row = l_tok + it * 32;
        fA[it] = *(const float4*)(feat + (size_t)(t0 + row) * D_MODEL + k0 + l_kg * 4);
    }
    if (tid < 128)
        wA = *(const float4*)(W + (size_t)(tid >> 3) * D_MODEL + k0 + (tid & 7) * 4);

    for (int kc = 0; kc < krange; kc += KCHUNK) {
        // store prefetched regs -> LDS
        #pragma unroll
        for (int it = 0; it < 4; ++it) {
            int row = l_tok + it * 32;
            int sw = (l_kg ^ ((row >> 2) & 7)) * 4;
            *(float4*)&f_lds[row][sw] = fA[it];
        }
        if (tid < 128)
            *(float4*)&w_lds[tid >> 3][(tid & 7) * 4] = wA;
        __syncthreads();

        // issue next chunk's global loads (overlap with compute below)
        if (kc + KCHUNK < krange) {
            #pragma unroll
            for (int it = 0; it < 4; ++it) {
                int row = l_tok + it * 32;
                fA[it] = *(const float4*)(feat + (size_t)(t0 + row) * D_MODEL + k0 + kc + KCHUNK + l_kg * 4);
            }
            if (tid < 128)
                wA = *(const float4*)(W + (size_t)(tid >> 3) * D_MODEL + k0 + kc + KCHUNK + (tid & 7) * 4);
        }

        #pragma unroll
        for (int kg = 0; kg < 8; ++kg) {
            int sw = (kg ^ (tg & 7)) * 4;
            float4 fv[4], wv[2];
            #pragma unroll
            for (int i = 0; i < 4; ++i)
                fv[i] = *(const float4*)&f_lds[tg * 4 + i][sw];
            #pragma unroll
            for (int j = 0; j < 2; ++j)
                wv[j] = *(const float4*)&w_lds[eg * 2 + j][kg * 4];
            #pragma unroll
            for (int i = 0; i < 4; ++i)
                #pragma unroll
                for (int j = 0; j < 2; ++j) {
                    acc[i][j] += fv[i].x * wv[j].x;
                    acc[i][j] += fv[i].y * wv[j].y;
                    acc[i][j] += fv[i].z * wv[j].z;
                    acc[i][j] += fv[i].w * wv[j].w;
                }
        }
        __syncthreads();
    }
    #pragma unroll
    for (int i = 0; i < 4; ++i) {
        int t = t0 + tg * 4 + i;
        float2 v = make_float2(acc[i][0], acc[i][1]);
        *(float2*)(partial + ((size_t)ks * T_TOK + t) * N_EXP + eg * 2) = v;
    }
}

// ---------------- Kernel A2: reduce partials + softmax + preference lists ----------------
__global__ __launch_bounds__(256) void finalize_kernel(
    const float* __restrict__ partial, const float* __restrict__ bias,
    unsigned long long* __restrict__ pref, float* __restrict__ probs, int ksplit)
{
    const int t = blockIdx.x * 256 + threadIdx.x;

    float aff[N_EXP];
    #pragma unroll
    for (int e = 0; e < N_EXP; ++e) aff[e] = 0.f;
    for (int ks = 0; ks < ksplit; ++ks) {
        const float4* p = (const float4*)(partial + ((size_t)ks * T_TOK + t) * N_EXP);
        #pragma unroll
        for (int q = 0; q < 4; ++q) {
            float4 v = p[q];
            aff[q*4+0] += v.x; aff[q*4+1] += v.y;
            aff[q*4+2] += v.z; aff[q*4+3] += v.w;
        }
    }
    #pragma unroll
    for (int e = 0; e < N_EXP; ++e) aff[e] += bias[e];

    float m = aff[0];
    #pragma unroll
    for (int e = 1; e < N_EXP; ++e) m = fmaxf(m, aff[e]);
    float s = 0.f;
    #pragma unroll
    for (int e = 0; e < N_EXP; ++e) s += __expf(aff[e] - m);

    float4* pr = (float4*)(probs + (size_t)t * N_EXP);
    #pragma unroll
    for (int q = 0; q < 4; ++q) {
        float4 v;
        v.x = __expf(aff[q*4+0] - m) / s;
        v.y = __expf(aff[q*4+1] - m) / s;
        v.z = __expf(aff[q*4+2] - m) / s;
        v.w = __expf(aff[q*4+3] - m) / s;
        pr[q] = v;
    }

    unsigned long long key[N_EXP];
    #pragma unroll
    for (int j = 0; j < N_EXP; ++j)
        key[j] = ((unsigned long long)f2ord(aff[j]) << 4) | (unsigned long long)(15 - j);
    unsigned long long p = 0ull;
    unsigned int used = 0;
    for (int r = 0; r < N_EXP; ++r) {
        unsigned long long bk = 0ull; int be = 0;
        for (int j = 0; j < N_EXP; ++j)
            if (!((used >> j) & 1u) && key[j] > bk) { bk = key[j]; be = j; }
        used |= (1u << be);
        p = (p << 4) | (unsigned long long)be;
    }
    pref[t] = p;
}

// ---------------- Kernel B: round-based balanced assignment (1 block, parallel phases) ----------------
__global__ __launch_bounds__(1024) void assign_kernel(
    const unsigned long long* __restrict__ pref,
    const float* __restrict__ probs,
    float* __restrict__ out0, float* __restrict__ out1)
{
    __shared__ unsigned char choice[T_TOK];
    __shared__ int cnt [NSEG][N_EXP + 1];
    __shared__ int pseg[NSEG][N_EXP + 1];
    __shared__ int rem_cap[N_EXP], cum_fill[N_EXP], fparr[N_EXP], addF[N_EXP];
    __shared__ int s_avail, s_start, s_pmin, s_fe;

    const int tid  = threadIdx.x;
    const int wave = tid >> 6, lane = tid & 63;
    const unsigned long long lt_mask = (1ull << lane) - 1ull;   // bits strictly below lane

    if (tid < N_EXP) { rem_cap[tid] = CAP; cum_fill[tid] = 0; }
    if (tid == 0) { s_avail = 0xFFFF; s_start = 0; s_fe = -1; }
    __syncthreads();

    for (int round = 0; round < N_EXP; ++round) {
        const int start = s_start;
        const unsigned int avail = (unsigned int)s_avail;
        const int feprev = s_fe;

        // P1: (re)compute choice = first available expert in pref order
        for (int t = start + tid; t < T_TOK; t += 1024) {
            bool walk = (round == 0) || ((int)choice[t] == feprev);
            if (walk) {
                unsigned long long pp = pref[t];
                int e = (int)(pp >> 60);
                while (!((avail >> e) & 1u)) { pp <<= 4; e = (int)(pp >> 60); }
                choice[t] = (unsigned char)e;
            }
        }
        __syncthreads();

        // P2: per-segment per-expert counts (ballot-based, all segments)
        for (int s = wave; s < NSEG; s += 16) {
            int t = s * 64 + lane;
            int c = (t >= start) ? (int)choice[t] : -1;
            #pragma unroll
            for (int e = 0; e < N_EXP; ++e) {
                unsigned long long mm = __ballot(c == e);
                if (lane == e) cnt[s][e] = (int)__popcll(mm);
            }
        }
        __syncthreads();

        // P3: wave w owns expert w. Parallel prefix over 128 segments (2/lane),
        // store exclusive prefixes, locate fill position via ballot.
        {
            const int e = wave;
            const int s0 = 2 * lane, s1 = 2 * lane + 1;
            const int c0 = cnt[s0][e], c1 = cnt[s1][e];
            const int pairsum = c0 + c1;
            int v = pairsum;
            #pragma unroll
            for (int d = 1; d < 64; d <<= 1) {
                int o = __shfl_up(v, d, 64);
                if (lane >= d) v += o;
            }
            const int excl0 = v - pairsum;
            const int excl1 = excl0 + c0;
            pseg[s0][e] = excl0;
            pseg[s1][e] = excl1;

            int fp = 0x7FFFFFFF;
            if ((avail >> e) & 1u) {
                const int need = rem_cap[e];
                int segc = 0x7FFFFFFF, kk = 0;
                if (excl0 < need && excl0 + c0 >= need)      { segc = s0; kk = need - excl0; }
                else if (excl1 < need && excl1 + c1 >= need) { segc = s1; kk = need - excl1; }
                unsigned long long b = __ballot(segc != 0x7FFFFFFF);
                if (b) {
                    int l = __builtin_ctzll(b);
                    int sstar = __shfl(segc, l, 64);
                    int k2    = __shfl(kk,   l, 64);
                    int t = sstar * 64 + lane;
                    int cc = (t >= start) ? (int)choice[t] : -1;
                    unsigned long long m = __ballot(cc == e);
                    int r = (int)__popcll(m & lt_mask);
                    bool hit = ((m >> lane) & 1ull) && (r == k2 - 1);
                    unsigned long long hb = __ballot(hit);
                    fp = sstar * 64 + __builtin_ctzll(hb);
                }
            }
            if (lane == 0) fparr[e] = fp;
        }
        __syncthreads();

        // P4: min over experts -> filling expert + position
        if (tid == 0) {
            int pm = 0x7FFFFFFF, f = 0;
            #pragma unroll
            for (int e = 0; e < N_EXP; ++e)
                if (fparr[e] < pm) { pm = fparr[e]; f = e; }
            s_pmin = pm; s_fe = f;
        }
        __syncthreads();

        const int pmin = s_pmin;
        const int segF = pmin >> 6;
        const int seg_lo = start >> 6;

        // P5: finalize tokens [start, pmin], write both outputs
        for (int s = seg_lo + wave; s <= segF; s += 16) {
            int t = s * 64 + lane;
            bool valid = (t >= start) && (t <= pmin);
            int c = valid ? (int)choice[t] : -1;
            unsigned long long own = 0ull;
            #pragma unroll
            for (int e = 0; e < N_EXP; ++e) {
                unsigned long long mm = __ballot(c == e);
                if (c == e) own = mm;
                if (s == segF && lane == e) addF[e] = (int)__popcll(mm);
            }
            if (valid) {
                int rank = pseg[s][c] + (int)__popcll(own & lt_mask);
                int pos  = cum_fill[c] + rank;
                out0[c * CAP + pos] = (float)t;
                out1[t] = probs[(size_t)t * N_EXP + c];
            }
        }
        __syncthreads();

        // P6: update per-expert state
        if (tid < N_EXP) {
            int fin = pseg[segF][tid] + addF[tid];
            cum_fill[tid] += fin;
            rem_cap[tid]  -= fin;
        }
        if (tid == 0) { s_avail &= ~(1 << s_fe); s_start = pmin + 1; }
        __syncthreads();
    }
}

extern "C" void kernel_launch(void* const* d_in, const int* in_sizes, int n_in,
                              void* d_out, int out_size, void* d_ws, size_t ws_size,
                              hipStream_t stream) {
    const float* feat = (const float*)d_in[0];
    const float* W    = (const float*)d_in[1];
    const float* bias = (const float*)d_in[2];

    float* out = (float*)d_out;
    char*  ws  = (char*)d_ws;

    const size_t per_split = (size_t)T_TOK * N_EXP * 4;   // 512 KB
    const size_t tail = (size_t)T_TOK * 8 + (size_t)T_TOK * N_EXP * 4;  // pref + probs
    int ksplit = (ws_size >= 8 * per_split + tail) ? 8 : 4;
    int krange = D_MODEL / ksplit;

    float* partial = (float*)ws;
    unsigned long long* pref = (unsigned long long*)(ws + (size_t)ksplit * per_split);
    float* probs = (float*)((char*)pref + (size_t)T_TOK * 8);

    hipLaunchKernelGGL(gemm_partial_kernel, dim3(T_TOK / TTILE, ksplit), dim3(256), 0, stream,
                       feat, W, partial, krange);
    hipLaunchKernelGGL(finalize_kernel, dim3(T_TOK / 256), dim3(256), 0, stream,
                       partial, bias, pref, probs, ksplit);
    hipLaunchKernelGGL(assign_kernel, dim3(1), dim3(1024), 0, stream,
                       pref, probs, out, out + T_TOK);
}

// Round 4
// 246.705 us; speedup vs baseline: 3.9644x; 1.0742x over previous
//
#include <hip/hip_runtime.h>
#include <hip/hip_bf16.h>
#include <math.h>

#define T_TOK 8192
#define D_MODEL 2048
#define N_EXP 16
#define CAP 512
#define NSEG (T_TOK / 64)           // 128

// ws layout:
// [0, 512KB)        : aff      float[T_TOK][N_EXP]
// [512KB, 576KB)    : pref64   u64[T_TOK]
// [576KB, 1088KB)   : probs    float[T_TOK][N_EXP]
// [1088KB, +8KB)    : tok2exp  u8[T_TOK]

__device__ __forceinline__ unsigned int f2ord(float f) {
    unsigned int b = __float_as_uint(f);
    return (b & 0x80000000u) ? ~b : (b | 0x80000000u);
}

// ---------------- Kernel A: full-K GEMM, W in LDS, butterfly reduce ----------------
// block = 256 threads (4 waves), 1 block/CU, 32 tokens/block (8/wave).
__global__ __launch_bounds__(256, 1) void gemm_aff_kernel(
    const float* __restrict__ feat, const float* __restrict__ W,
    float* __restrict__ aff)
{
    __shared__ float w_lds[N_EXP * D_MODEL];   // 128 KB

    const int tid  = threadIdx.x;
    const int wave = tid >> 6, lane = tid & 63;
    const int t0   = blockIdx.x * 32;

    // stage full W into LDS (flat copy, coalesced)
    for (int i = tid; i < N_EXP * D_MODEL / 4; i += 256)
        ((float4*)w_lds)[i] = ((const float4*)W)[i];
    __syncthreads();

    const float* fbase = feat + (size_t)(t0 + wave * 8) * D_MODEL + lane * 4;

    float acc[128];
    #pragma unroll
    for (int i = 0; i < 128; ++i) acc[i] = 0.f;

    float4 cur[8], nxt[8];
    #pragma unroll
    for (int r = 0; r < 8; ++r)
        cur[r] = *(const float4*)(fbase + (size_t)r * D_MODEL);

    #pragma unroll
    for (int j = 0; j < 8; ++j) {          // 8 k-blocks of 256 floats
        if (j < 7) {
            #pragma unroll
            for (int r = 0; r < 8; ++r)
                nxt[r] = *(const float4*)(fbase + (size_t)r * D_MODEL + (j + 1) * 256);
        }
        const int kbase = j * 256 + lane * 4;
        #pragma unroll
        for (int e = 0; e < N_EXP; ++e) {
            float4 wv = *(const float4*)&w_lds[e * D_MODEL + kbase];
            #pragma unroll
            for (int r = 0; r < 8; ++r) {
                acc[r * 16 + e] += cur[r].x * wv.x;
                acc[r * 16 + e] += cur[r].y * wv.y;
                acc[r * 16 + e] += cur[r].z * wv.z;
                acc[r * 16 + e] += cur[r].w * wv.w;
            }
        }
        #pragma unroll
        for (int r = 0; r < 8; ++r) cur[r] = nxt[r];
    }

    // halving butterfly reduce over 64 lanes: 128 slots -> 2 slots/lane.
    // step with mask m consumes slot MSB: lanes with (lane&m) keep hi half.
    #pragma unroll
    for (int step = 0; step < 6; ++step) {
        const int m    = 1 << step;
        const int half = 128 >> (step + 1);
        const bool hi  = (lane & m) != 0;
        #pragma unroll
        for (int jj = 0; jj < half; ++jj) {
            float send = hi ? acc[jj] : acc[jj + half];
            float recv = __shfl_xor(send, m, 64);
            acc[jj] = (hi ? acc[jj + half] : acc[jj]) + recv;
        }
    }
    // slot id: bit6..bit1 = lane bit0..bit5 (bit-reversed), bit0 = reg index
    const int rl = ((lane & 1) << 5) | (((lane >> 1) & 1) << 4) | (((lane >> 2) & 1) << 3)
                 | (((lane >> 3) & 1) << 2) | (((lane >> 4) & 1) << 1) | ((lane >> 5) & 1);
    #pragma unroll
    for (int jj = 0; jj < 2; ++jj) {
        int slot = (rl << 1) | jj;
        int r = slot >> 4, e = slot & 15;
        aff[(size_t)(t0 + wave * 8 + r) * N_EXP + e] = acc[jj];
    }
}

// ---------------- Kernel B: softmax + preference lists (reads aff) ----------------
__global__ __launch_bounds__(256) void finalize_kernel(
    const float* __restrict__ aff_in, const float* __restrict__ bias,
    unsigned long long* __restrict__ pref, float* __restrict__ probs)
{
    const int t = blockIdx.x * 256 + threadIdx.x;

    float aff[N_EXP];
    const float4* p = (const float4*)(aff_in + (size_t)t * N_EXP);
    #pragma unroll
    for (int q = 0; q < 4; ++q) {
        float4 v = p[q];
        aff[q*4+0] = v.x; aff[q*4+1] = v.y; aff[q*4+2] = v.z; aff[q*4+3] = v.w;
    }
    #pragma unroll
    for (int e = 0; e < N_EXP; ++e) aff[e] += bias[e];

    float m = aff[0];
    #pragma unroll
    for (int e = 1; e < N_EXP; ++e) m = fmaxf(m, aff[e]);
    float s = 0.f;
    #pragma unroll
    for (int e = 0; e < N_EXP; ++e) s += __expf(aff[e] - m);

    float4* pr = (float4*)(probs + (size_t)t * N_EXP);
    #pragma unroll
    for (int q = 0; q < 4; ++q) {
        float4 v;
        v.x = __expf(aff[q*4+0] - m) / s;
        v.y = __expf(aff[q*4+1] - m) / s;
        v.z = __expf(aff[q*4+2] - m) / s;
        v.w = __expf(aff[q*4+3] - m) / s;
        pr[q] = v;
    }

    unsigned long long key[N_EXP];
    #pragma unroll
    for (int j = 0; j < N_EXP; ++j)
        key[j] = ((unsigned long long)f2ord(aff[j]) << 4) | (unsigned long long)(15 - j);
    unsigned long long pk = 0ull;
    unsigned int used = 0;
    for (int r = 0; r < N_EXP; ++r) {
        unsigned long long bk = 0ull; int be = 0;
        for (int j = 0; j < N_EXP; ++j)
            if (!((used >> j) & 1u) && key[j] > bk) { bk = key[j]; be = j; }
        used |= (1u << be);
        pk = (pk << 4) | (unsigned long long)be;
    }
    pref[t] = pk;
}

// ---------------- Kernel C: balanced assignment, register-resident ----------------
// wave w owns segments w*8..w*8+7; lane l owns token s*64+l of each.
__global__ __launch_bounds__(1024) void assign_kernel(
    const unsigned long long* __restrict__ pref,
    float* __restrict__ out0, unsigned char* __restrict__ tok2exp)
{
    __shared__ unsigned char choiceL[T_TOK];      // cross-wave search mirror
    __shared__ int cnt [NSEG][N_EXP + 1];
    __shared__ int pseg[NSEG][N_EXP + 1];
    __shared__ int rem_cap[N_EXP], cum_fill[N_EXP], fparr[N_EXP], addF[N_EXP];
    __shared__ int s_avail, s_start, s_pmin, s_fe;

    const int tid  = threadIdx.x;
    const int wave = tid >> 6, lane = tid & 63;
    const unsigned long long lt_mask = (1ull << lane) - 1ull;

    unsigned long long pf[8];
    int ch[8];
    #pragma unroll
    for (int i = 0; i < 8; ++i)
        pf[i] = pref[wave * 512 + i * 64 + lane];   // coalesced

    // round-0 choice + counts
    #pragma unroll
    for (int i = 0; i < 8; ++i) {
        const int s = wave * 8 + i;
        ch[i] = (int)(pf[i] >> 60);
        choiceL[s * 64 + lane] = (unsigned char)ch[i];
        #pragma unroll
        for (int e = 0; e < N_EXP; ++e) {
            unsigned long long mm = __ballot(ch[i] == e);
            if (lane == e) cnt[s][e] = (int)__popcll(mm);
        }
    }
    if (tid < N_EXP) { rem_cap[tid] = CAP; cum_fill[tid] = 0; }
    if (tid == 0) { s_avail = 0xFFFF; s_start = 0; }
    __syncthreads();

    for (int round = 0; round < N_EXP; ++round) {
        const int start = s_start;
        const unsigned int avail = (unsigned int)s_avail;

        // P3: wave w owns expert w; prefix-scan cnt over 128 segments (2/lane),
        // locate fill position via ballot.
        {
            const int e = wave;
            const int s0 = 2 * lane, s1 = s0 + 1;
            const int c0 = cnt[s0][e], c1 = cnt[s1][e];
            const int pairsum = c0 + c1;
            int v = pairsum;
            #pragma unroll
            for (int d = 1; d < 64; d <<= 1) {
                int o = __shfl_up(v, d, 64);
                if (lane >= d) v += o;
            }
            const int excl0 = v - pairsum;
            const int excl1 = excl0 + c0;
            pseg[s0][e] = excl0;
            pseg[s1][e] = excl1;

            int fp = 0x7FFFFFFF;
            if ((avail >> e) & 1u) {
                const int need = rem_cap[e];
                int segc = 0x7FFFFFFF, kk = 0;
                if (excl0 < need && excl0 + c0 >= need)      { segc = s0; kk = need - excl0; }
                else if (excl1 < need && excl1 + c1 >= need) { segc = s1; kk = need - excl1; }
                unsigned long long b = __ballot(segc != 0x7FFFFFFF);
                if (b) {
                    int l2    = __builtin_ctzll(b);
                    int sstar = __shfl(segc, l2, 64);
                    int k2    = __shfl(kk,   l2, 64);
                    int t = sstar * 64 + lane;
                    int cc = (t >= start) ? (int)choiceL[t] : -1;
                    unsigned long long m = __ballot(cc == e);
                    int r = (int)__popcll(m & lt_mask);
                    bool hit = ((m >> lane) & 1ull) && (r == k2 - 1);
                    unsigned long long hb = __ballot(hit);
                    fp = sstar * 64 + __builtin_ctzll(hb);
                }
            }
            if (lane == 0) fparr[e] = fp;
        }
        __syncthreads();

        // P4: earliest fill event
        if (tid == 0) {
            int pm = 0x7FFFFFFF, f = 0;
            #pragma unroll
            for (int e = 0; e < N_EXP; ++e)
                if (fparr[e] < pm) { pm = fparr[e]; f = e; }
            s_pmin = pm; s_fe = f;
        }
        __syncthreads();

        const int pmin = s_pmin;
        const int fe   = s_fe;
        const int segF = pmin >> 6;
        const int seg_lo = start >> 6;

        // P5: finalize own segments in [seg_lo, segF]; write out0; recount cnt
        #pragma unroll
        for (int i = 0; i < 8; ++i) {
            const int s = wave * 8 + i;
            if (s < seg_lo || s > segF) continue;
            const int t = s * 64 + lane;
            const bool valid = (t >= start) && (t <= pmin);
            const int c = valid ? ch[i] : -1;
            unsigned long long own = 0ull;
            #pragma unroll
            for (int e2 = 0; e2 < N_EXP; ++e2) {
                unsigned long long mm = __ballot(c == e2);
                if (c == e2) own = mm;
                if (s == segF && lane == e2) addF[e2] = (int)__popcll(mm);
                unsigned long long mm2 = __ballot((t > pmin) && (ch[i] == e2));
                if (lane == e2) cnt[s][e2] = (int)__popcll(mm2);
            }
            if (valid) {
                int rank = pseg[s][c] + (int)__popcll(own & lt_mask);
                out0[c * CAP + cum_fill[c] + rank] = (float)t;
            }
        }
        __syncthreads();

        // P6: state update
        if (tid < N_EXP) {
            int fin = pseg[segF][tid] + addF[tid];
            cum_fill[tid] += fin;
            rem_cap[tid]  -= fin;
        }
        if (tid == 0) { s_avail &= ~(1 << fe); s_start = pmin + 1; }

        // P7: rewalk tokens whose choice was the filled expert; recount dirty segs
        if (round < N_EXP - 1) {
            const unsigned int navail = avail & ~(1u << fe);
            #pragma unroll
            for (int i = 0; i < 8; ++i) {
                const int s = wave * 8 + i;
                const int t = s * 64 + lane;
                const bool rw = (t > pmin) && (ch[i] == fe);
                unsigned long long mb = __ballot(rw);
                if (rw) {
                    unsigned long long pp = pf[i];
                    int e2 = (int)(pp >> 60);
                    while (!((navail >> e2) & 1u)) { pp <<= 4; e2 = (int)(pp >> 60); }
                    ch[i] = e2;
                    choiceL[t] = (unsigned char)e2;
                }
                if (mb) {
                    #pragma unroll
                    for (int e2 = 0; e2 < N_EXP; ++e2) {
                        unsigned long long mm = __ballot((t > pmin) && (ch[i] == e2));
                        if (lane == e2) cnt[s][e2] = (int)__popcll(mm);
                    }
                }
            }
        }
        __syncthreads();
    }

    // export final assignment for the gather kernel (coalesced u8)
    #pragma unroll
    for (int i = 0; i < 8; ++i)
        tok2exp[wave * 512 + i * 64 + lane] = (unsigned char)ch[i];
}

// ---------------- Kernel D: gather routing probs ----------------
__global__ __launch_bounds__(256) void gather_kernel(
    const float* __restrict__ probs, const unsigned char* __restrict__ tok2exp,
    float* __restrict__ out1)
{
    const int t = blockIdx.x * 256 + threadIdx.x;
    out1[t] = probs[(size_t)t * N_EXP + tok2exp[t]];
}

extern "C" void kernel_launch(void* const* d_in, const int* in_sizes, int n_in,
                              void* d_out, int out_size, void* d_ws, size_t ws_size,
                              hipStream_t stream) {
    const float* feat = (const float*)d_in[0];
    const float* W    = (const float*)d_in[1];
    const float* bias = (const float*)d_in[2];

    float* out = (float*)d_out;
    char*  ws  = (char*)d_ws;

    float* aff                = (float*)ws;                                  // 512 KB
    unsigned long long* pref  = (unsigned long long*)(ws + (size_t)T_TOK * N_EXP * 4);
    float* probs              = (float*)((char*)pref + (size_t)T_TOK * 8);   // 512 KB
    unsigned char* tok2exp    = (unsigned char*)((char*)probs + (size_t)T_TOK * N_EXP * 4);

    hipLaunchKernelGGL(gemm_aff_kernel, dim3(T_TOK / 32), dim3(256), 0, stream,
                       feat, W, aff);
    hipLaunchKernelGGL(finalize_kernel, dim3(T_TOK / 256), dim3(256), 0, stream,
                       aff, bias, pref, probs);
    hipLaunchKernelGGL(assign_kernel, dim3(1), dim3(1024), 0, stream,
                       pref, out, tok2exp);
    hipLaunchKernelGGL(gather_kernel, dim3(T_TOK / 256), dim3(256), 0, stream,
                       probs, tok2exp, out + T_TOK);
}

// Round 5
// 197.763 us; speedup vs baseline: 4.9455x; 1.2475x over previous
//
#include <hip/hip_runtime.h>
#include <hip/hip_bf16.h>
#include <math.h>

#define T_TOK 8192
#define D_MODEL 2048
#define N_EXP 16
#define CAP 512
#define NSEG (T_TOK / 64)           // 128
#define KSPLIT 2
#define KRANGE (D_MODEL / KSPLIT)   // 1024

// ws layout (bytes):
// partial: 0         .. 1048576   float[2][T_TOK][16]
// pref:    1048576   .. +65536    u64[T_TOK]
// probs:   1114112   .. +524288   float[T_TOK][16]
// choice0: 1638400   .. +8192     u8[T_TOK]
// cnt0:    1646592   .. +8192     int[NSEG][16]
// evt:     1654784   .. +128      int[32] (evp[16], evf[16])
// t2e:     1654912   .. +8192     u8[T_TOK]
// bcnt:    1663104   .. +2048     int[32][16]

__device__ __forceinline__ unsigned int f2ord(float f) {
    unsigned int b = __float_as_uint(f);
    return (b & 0x80000000u) ? ~b : (b | 0x80000000u);
}

// ---------------- Kernel 1: K-split GEMM, W-chunk in LDS, butterfly reduce ----------------
// 512 blocks (256 token-tiles x 2 K-splits), 256 thr, 2 blocks/CU, 2 waves/SIMD.
__global__ __launch_bounds__(256, 2) void gemm_partial_kernel(
    const float* __restrict__ feat, const float* __restrict__ W,
    float* __restrict__ partial)
{
    __shared__ float w_lds[N_EXP * KRANGE];   // 64 KB

    const int tid  = threadIdx.x;
    const int wave = tid >> 6, lane = tid & 63;
    const int t0   = (blockIdx.x & 255) * 32;
    const int ks   = blockIdx.x >> 8;
    const int k0   = ks * KRANGE;

    // stage W chunk (16 rows x KRANGE)
    for (int i = tid; i < N_EXP * KRANGE / 4; i += 256) {
        int e = i / (KRANGE / 4), r = i % (KRANGE / 4);
        ((float4*)w_lds)[i] = *(const float4*)(W + (size_t)e * D_MODEL + k0 + r * 4);
    }
    __syncthreads();

    const float* fbase = feat + (size_t)(t0 + wave * 8) * D_MODEL + k0 + lane * 4;

    float acc[128];
    #pragma unroll
    for (int i = 0; i < 128; ++i) acc[i] = 0.f;

    float4 cur[8], nxt[8];
    #pragma unroll
    for (int r = 0; r < 8; ++r)
        cur[r] = *(const float4*)(fbase + (size_t)r * D_MODEL);

    #pragma unroll
    for (int j = 0; j < KRANGE / 256; ++j) {       // 4 k-subblocks of 256 floats
        if (j < KRANGE / 256 - 1) {
            #pragma unroll
            for (int r = 0; r < 8; ++r)
                nxt[r] = *(const float4*)(fbase + (size_t)r * D_MODEL + (j + 1) * 256);
        }
        const int kbase = j * 256 + lane * 4;
        #pragma unroll
        for (int e = 0; e < N_EXP; ++e) {
            float4 wv = *(const float4*)&w_lds[e * KRANGE + kbase];
            #pragma unroll
            for (int r = 0; r < 8; ++r) {
                acc[r * 16 + e] += cur[r].x * wv.x;
                acc[r * 16 + e] += cur[r].y * wv.y;
                acc[r * 16 + e] += cur[r].z * wv.z;
                acc[r * 16 + e] += cur[r].w * wv.w;
            }
        }
        #pragma unroll
        for (int r = 0; r < 8; ++r) cur[r] = nxt[r];
    }

    // halving butterfly reduce: 128 slots -> 2 slots/lane (verified in r4)
    #pragma unroll
    for (int step = 0; step < 6; ++step) {
        const int m    = 1 << step;
        const int half = 128 >> (step + 1);
        const bool hi  = (lane & m) != 0;
        #pragma unroll
        for (int jj = 0; jj < half; ++jj) {
            float send = hi ? acc[jj] : acc[jj + half];
            float recv = __shfl_xor(send, m, 64);
            acc[jj] = (hi ? acc[jj + half] : acc[jj]) + recv;
        }
    }
    const int rl = ((lane & 1) << 5) | (((lane >> 1) & 1) << 4) | (((lane >> 2) & 1) << 3)
                 | (((lane >> 3) & 1) << 2) | (((lane >> 4) & 1) << 1) | ((lane >> 5) & 1);
    #pragma unroll
    for (int jj = 0; jj < 2; ++jj) {
        int slot = (rl << 1) | jj;
        int r = slot >> 4, e = slot & 15;
        partial[((size_t)ks * T_TOK + t0 + wave * 8 + r) * N_EXP + e] = acc[jj];
    }
}

// ---------------- Kernel 2: reduce splits + softmax + pref lists + choice0 + seg counts ----------------
__global__ __launch_bounds__(256) void finalize_kernel(
    const float* __restrict__ partial, const float* __restrict__ bias,
    unsigned long long* __restrict__ pref, float* __restrict__ probs,
    unsigned char* __restrict__ choice0, int* __restrict__ cnt0)
{
    const int tid = threadIdx.x;
    const int t = blockIdx.x * 256 + tid;
    const int wave = tid >> 6, lane = tid & 63;

    float aff[N_EXP];
    {
        const float4* p0 = (const float4*)(partial + (size_t)t * N_EXP);
        const float4* p1 = (const float4*)(partial + ((size_t)T_TOK + t) * N_EXP);
        #pragma unroll
        for (int q = 0; q < 4; ++q) {
            float4 a = p0[q], b = p1[q];
            aff[q*4+0] = a.x + b.x; aff[q*4+1] = a.y + b.y;
            aff[q*4+2] = a.z + b.z; aff[q*4+3] = a.w + b.w;
        }
    }
    #pragma unroll
    for (int e = 0; e < N_EXP; ++e) aff[e] += bias[e];

    float m = aff[0];
    #pragma unroll
    for (int e = 1; e < N_EXP; ++e) m = fmaxf(m, aff[e]);
    float s = 0.f;
    #pragma unroll
    for (int e = 0; e < N_EXP; ++e) s += __expf(aff[e] - m);

    float4* pr = (float4*)(probs + (size_t)t * N_EXP);
    #pragma unroll
    for (int q = 0; q < 4; ++q) {
        float4 v;
        v.x = __expf(aff[q*4+0] - m) / s;
        v.y = __expf(aff[q*4+1] - m) / s;
        v.z = __expf(aff[q*4+2] - m) / s;
        v.w = __expf(aff[q*4+3] - m) / s;
        pr[q] = v;
    }

    unsigned long long key[N_EXP];
    #pragma unroll
    for (int j = 0; j < N_EXP; ++j)
        key[j] = ((unsigned long long)f2ord(aff[j]) << 4) | (unsigned long long)(15 - j);
    unsigned long long pk = 0ull;
    unsigned int used = 0;
    for (int r = 0; r < N_EXP; ++r) {
        unsigned long long bk = 0ull; int be = 0;
        for (int j = 0; j < N_EXP; ++j)
            if (!((used >> j) & 1u) && key[j] > bk) { bk = key[j]; be = j; }
        used |= (1u << be);
        pk = (pk << 4) | (unsigned long long)be;
    }
    pref[t] = pk;

    const int c = (int)(pk >> 60);
    choice0[t] = (unsigned char)c;
    // per-segment counts: wave w of block b covers segment b*4+w exactly
    #pragma unroll
    for (int e = 0; e < N_EXP; ++e) {
        unsigned long long mm = __ballot(c == e);
        if (lane == e) cnt0[(blockIdx.x * 4 + wave) * N_EXP + e] = (int)__popcll(mm);
    }
}

// ---------------- Kernel 3: fill-event schedule (1 block, 512 thr) ----------------
__global__ __launch_bounds__(512) void events_kernel(
    const unsigned long long* __restrict__ pref,
    const unsigned char* __restrict__ choice0,
    const int* __restrict__ cnt0, int* __restrict__ evt)
{
    __shared__ unsigned char choiceL[T_TOK];
    __shared__ int cnt [NSEG][N_EXP + 1];
    __shared__ int pseg[NSEG][N_EXP + 1];
    __shared__ int rem_cap[N_EXP], fparr[N_EXP], addF[N_EXP];
    __shared__ int s_avail, s_start, s_pmin, s_fe, s_seglo;
    __shared__ int evp[N_EXP], evf[N_EXP];

    const int tid  = threadIdx.x;
    const int wave = tid >> 6, lane = tid & 63;
    const unsigned long long lt_mask = (1ull << lane) - 1ull;

    for (int i = tid; i < T_TOK / 4; i += 512)
        ((unsigned int*)choiceL)[i] = ((const unsigned int*)choice0)[i];
    for (int i = tid; i < NSEG * N_EXP; i += 512)
        cnt[i >> 4][i & 15] = cnt0[i];
    if (tid < N_EXP) rem_cap[tid] = CAP;
    if (tid == 0) { s_avail = 0xFFFF; s_start = 0; s_seglo = 0; }
    __syncthreads();

    for (int round = 0; round < N_EXP; ++round) {
        const int start = s_start;
        const unsigned int avail = (unsigned int)s_avail;
        const int seglo = s_seglo;

        // A: per-expert scan + crossing locate (each wave owns experts w, w+8)
        #pragma unroll
        for (int ee = 0; ee < 2; ++ee) {
            const int e = wave + ee * 8;
            const int s0 = 2 * lane, s1 = s0 + 1;
            const int c0 = (s0 >= seglo) ? cnt[s0][e] : 0;
            const int c1 = (s1 >= seglo) ? cnt[s1][e] : 0;
            const int pairsum = c0 + c1;
            int v = pairsum;
            #pragma unroll
            for (int d = 1; d < 64; d <<= 1) {
                int o = __shfl_up(v, d, 64);
                if (lane >= d) v += o;
            }
            const int excl0 = v - pairsum;
            const int excl1 = excl0 + c0;
            pseg[s0][e] = excl0;
            pseg[s1][e] = excl1;

            int fp = 0x7FFFFFFF;
            if ((avail >> e) & 1u) {
                const int need = rem_cap[e];
                int segc = 0x7FFFFFFF, kk = 0;
                if (excl0 < need && excl0 + c0 >= need)      { segc = s0; kk = need - excl0; }
                else if (excl1 < need && excl1 + c1 >= need) { segc = s1; kk = need - excl1; }
                unsigned long long b = __ballot(segc != 0x7FFFFFFF);
                if (b) {
                    int l2    = __builtin_ctzll(b);
                    int sstar = __shfl(segc, l2, 64);
                    int k2    = __shfl(kk,   l2, 64);
                    int t = sstar * 64 + lane;
                    int cc = (t >= start) ? (int)choiceL[t] : -1;
                    unsigned long long m = __ballot(cc == e);
                    int r = (int)__popcll(m & lt_mask);
                    bool hit = ((m >> lane) & 1ull) && (r == k2 - 1);
                    unsigned long long hb = __ballot(hit);
                    fp = sstar * 64 + __builtin_ctzll(hb);
                }
            }
            if (lane == 0) fparr[e] = fp;
        }
        __syncthreads();

        if (tid == 0) {
            int pm = 0x7FFFFFFF, f = 0;
            #pragma unroll
            for (int e = 0; e < N_EXP; ++e)
                if (fparr[e] < pm) { pm = fparr[e]; f = e; }
            s_pmin = pm; s_fe = f;
        }
        __syncthreads();
        const int pmin = s_pmin, fe = s_fe;
        const int segF = pmin >> 6;

        // addF: count finalized tokens inside boundary segment
        if (wave == 0) {
            int t = segF * 64 + lane;
            int cc = (t >= start && t <= pmin) ? (int)choiceL[t] : -1;
            #pragma unroll
            for (int e = 0; e < N_EXP; ++e) {
                unsigned long long mm = __ballot(cc == e);
                if (lane == e) addF[e] = (int)__popcll(mm);
            }
        }
        __syncthreads();

        if (tid < N_EXP) rem_cap[tid] -= pseg[segF][tid] + addF[tid];
        if (tid == 0) {
            evp[round] = pmin; evf[round] = fe;
            s_avail = (int)(avail & ~(1u << fe));
            s_start = pmin + 1;
            s_seglo = segF;
        }
        __syncthreads();

        if (round < N_EXP - 1) {
            const unsigned int navail = (unsigned int)s_avail;
            // D: rewalk tail tokens whose choice was the filled expert
            for (int t = pmin + 1 + tid; t < T_TOK; t += 512) {
                if ((int)choiceL[t] == fe) {
                    unsigned long long pp = pref[t];
                    int e2 = (int)(pp >> 60);
                    while (!((navail >> e2) & 1u)) { pp <<= 4; e2 = (int)(pp >> 60); }
                    choiceL[t] = (unsigned char)e2;
                }
            }
            __syncthreads();
            // E: recount tail segments (excluding finalized part of segF)
            for (int s = segF + wave; s < NSEG; s += 8) {
                int t = s * 64 + lane;
                int cc = (t > pmin) ? (int)choiceL[t] : -1;
                #pragma unroll
                for (int e = 0; e < N_EXP; ++e) {
                    unsigned long long mm = __ballot(cc == e);
                    if (lane == e) cnt[s][e] = (int)__popcll(mm);
                }
            }
            __syncthreads();
        }
    }

    if (tid < N_EXP) { evt[tid] = evp[tid]; evt[N_EXP + tid] = evf[tid]; }
}

// ---------------- Kernel 4: final choice per token + per-block expert counts ----------------
__global__ __launch_bounds__(256) void choice_kernel(
    const unsigned long long* __restrict__ pref, const int* __restrict__ evt,
    unsigned char* __restrict__ t2e, int* __restrict__ bcnt)
{
    __shared__ int evp[N_EXP], evf[N_EXP];
    __shared__ int sc[4][N_EXP];
    const int tid = threadIdx.x, b = blockIdx.x;
    const int wave = tid >> 6, lane = tid & 63;
    if (tid < N_EXP) evp[tid] = evt[tid];
    else if (tid < 2 * N_EXP) evf[tid - N_EXP] = evt[tid];
    __syncthreads();

    const int t = b * 256 + tid;
    unsigned int mask = 0xFFFFu;
    #pragma unroll
    for (int j = 0; j < N_EXP; ++j)
        if (evp[j] < t) mask &= ~(1u << evf[j]);

    unsigned long long pp = pref[t];
    int e = (int)(pp >> 60);
    while (!((mask >> e) & 1u)) { pp <<= 4; e = (int)(pp >> 60); }
    t2e[t] = (unsigned char)e;

    #pragma unroll
    for (int e2 = 0; e2 < N_EXP; ++e2) {
        unsigned long long mm = __ballot(e == e2);
        if (lane == e2) sc[wave][e2] = (int)__popcll(mm);
    }
    __syncthreads();
    if (tid < N_EXP)
        bcnt[b * N_EXP + tid] = sc[0][tid] + sc[1][tid] + sc[2][tid] + sc[3][tid];
}

// ---------------- Kernel 5: ranks + write out0/out1 ----------------
__global__ __launch_bounds__(256) void writeout_kernel(
    const unsigned char* __restrict__ t2e, const int* __restrict__ bcnt,
    const float* __restrict__ probs,
    float* __restrict__ out0, float* __restrict__ out1)
{
    __shared__ int base[N_EXP];
    __shared__ int sc[4][N_EXP];
    const int tid = threadIdx.x, b = blockIdx.x;
    const int wave = tid >> 6, lane = tid & 63;
    const unsigned long long lt_mask = (1ull << lane) - 1ull;

    const int t = b * 256 + tid;
    const int c = (int)t2e[t];

    unsigned long long own = 0ull;
    #pragma unroll
    for (int e2 = 0; e2 < N_EXP; ++e2) {
        unsigned long long mm = __ballot(c == e2);
        if (c == e2) own = mm;
        if (lane == e2) sc[wave][e2] = (int)__popcll(mm);
    }
    if (tid < N_EXP) {
        int s = 0;
        for (int b2 = 0; b2 < b; ++b2) s += bcnt[b2 * N_EXP + tid];
        base[tid] = s;
    }
    __syncthreads();

    int rank = (int)__popcll(own & lt_mask);
    for (int w2 = 0; w2 < wave; ++w2) rank += sc[w2][c];
    const int pos = base[c] + rank;
    out0[c * CAP + pos] = (float)t;
    out1[t] = probs[(size_t)t * N_EXP + c];
}

extern "C" void kernel_launch(void* const* d_in, const int* in_sizes, int n_in,
                              void* d_out, int out_size, void* d_ws, size_t ws_size,
                              hipStream_t stream) {
    const float* feat = (const float*)d_in[0];
    const float* W    = (const float*)d_in[1];
    const float* bias = (const float*)d_in[2];

    float* out = (float*)d_out;
    char*  ws  = (char*)d_ws;

    float* partial           = (float*)ws;
    unsigned long long* pref = (unsigned long long*)(ws + 1048576);
    float* probs             = (float*)(ws + 1114112);
    unsigned char* choice0   = (unsigned char*)(ws + 1638400);
    int* cnt0                = (int*)(ws + 1646592);
    int* evt                 = (int*)(ws + 1654784);
    unsigned char* t2e       = (unsigned char*)(ws + 1654912);
    int* bcnt                = (int*)(ws + 1663104);

    hipLaunchKernelGGL(gemm_partial_kernel, dim3(512), dim3(256), 0, stream,
                       feat, W, partial);
    hipLaunchKernelGGL(finalize_kernel, dim3(T_TOK / 256), dim3(256), 0, stream,
                       partial, bias, pref, probs, choice0, cnt0);
    hipLaunchKernelGGL(events_kernel, dim3(1), dim3(512), 0, stream,
                       pref, choice0, cnt0, evt);
    hipLaunchKernelGGL(choice_kernel, dim3(T_TOK / 256), dim3(256), 0, stream,
                       pref, evt, t2e, bcnt);
    hipLaunchKernelGGL(writeout_kernel, dim3(T_TOK / 256), dim3(256), 0, stream,
                       t2e, bcnt, probs, out, out + T_TOK);
}

// Round 6
// 191.601 us; speedup vs baseline: 5.1045x; 1.0322x over previous
//
#include <hip/hip_runtime.h>
#include <hip/hip_bf16.h>
#include <math.h>

#define T_TOK 8192
#define D_MODEL 2048
#define N_EXP 16
#define CAP 512
#define NSEG (T_TOK / 64)           // 128

// ws layout (bytes):
// aff:   0       .. 524288    float[T_TOK][16]
// pref:  524288  .. +65536    u64[T_TOK]
// probs: 589824  .. +524288   float[T_TOK][16]
// evt:   1114112 .. +128      int[32] (evp[16], evf[16])
// t2e:   1114240 .. +8192     u8[T_TOK]
// bcnt:  1122432 .. +2048     int[32][16]

__device__ __forceinline__ unsigned int f2ord(float f) {
    unsigned int b = __float_as_uint(f);
    return (b & 0x80000000u) ? ~b : (b | 0x80000000u);
}

// ---------------- Kernel 1: full-K GEMM, no LDS, W via L1/L2, butterfly reduce ----------------
// 512 blocks x 256 thr; 4 waves/SIMD; wave owns 4 tokens; lane slices K (32 floats).
__global__ __launch_bounds__(256, 4) void gemm_aff_kernel(
    const float* __restrict__ feat, const float* __restrict__ W,
    float* __restrict__ aff)
{
    const int tid  = threadIdx.x;
    const int wave = tid >> 6, lane = tid & 63;
    const int tbase = blockIdx.x * 16 + wave * 4;

    const float* fbase = feat + (size_t)tbase * D_MODEL + lane * 4;

    float acc[64];   // acc[r*16+e]
    #pragma unroll
    for (int i = 0; i < 64; ++i) acc[i] = 0.f;

    float4 cur[4], nxt[4];
    #pragma unroll
    for (int r = 0; r < 4; ++r)
        cur[r] = *(const float4*)(fbase + (size_t)r * D_MODEL);

    #pragma unroll
    for (int j = 0; j < 8; ++j) {               // 8 k-blocks of 256 floats
        if (j < 7) {
            #pragma unroll
            for (int r = 0; r < 4; ++r)
                nxt[r] = *(const float4*)(fbase + (size_t)r * D_MODEL + (j + 1) * 256);
        }
        const float* wbase = W + j * 256 + lane * 4;
        #pragma unroll
        for (int g = 0; g < 4; ++g) {           // experts in groups of 4 (reg pressure)
            float4 wv[4];
            #pragma unroll
            for (int i = 0; i < 4; ++i)
                wv[i] = *(const float4*)(wbase + (size_t)(g * 4 + i) * D_MODEL);
            #pragma unroll
            for (int i = 0; i < 4; ++i)
                #pragma unroll
                for (int r = 0; r < 4; ++r) {
                    acc[r * 16 + g * 4 + i] += cur[r].x * wv[i].x;
                    acc[r * 16 + g * 4 + i] += cur[r].y * wv[i].y;
                    acc[r * 16 + g * 4 + i] += cur[r].z * wv[i].z;
                    acc[r * 16 + g * 4 + i] += cur[r].w * wv[i].w;
                }
        }
        #pragma unroll
        for (int r = 0; r < 4; ++r) cur[r] = nxt[r];
    }

    // halving butterfly: 64 slots -> 1 slot/lane (r4/r5-verified pattern)
    #pragma unroll
    for (int step = 0; step < 6; ++step) {
        const int m    = 1 << step;
        const int half = 64 >> (step + 1);
        const bool hi  = (lane & m) != 0;
        #pragma unroll
        for (int jj = 0; jj < half; ++jj) {
            float send = hi ? acc[jj] : acc[jj + half];
            float recv = __shfl_xor(send, m, 64);
            acc[jj] = (hi ? acc[jj + half] : acc[jj]) + recv;
        }
    }
    const int slot = ((lane & 1) << 5) | (((lane >> 1) & 1) << 4) | (((lane >> 2) & 1) << 3)
                   | (((lane >> 3) & 1) << 2) | (((lane >> 4) & 1) << 1) | ((lane >> 5) & 1);
    const int r = slot >> 4, e = slot & 15;
    aff[(size_t)(tbase + r) * N_EXP + e] = acc[0];
}

// ---------------- Kernel 2: bias + softmax + preference lists ----------------
__global__ __launch_bounds__(256) void finalize_kernel(
    const float* __restrict__ aff_in, const float* __restrict__ bias,
    unsigned long long* __restrict__ pref, float* __restrict__ probs)
{
    const int t = blockIdx.x * 256 + threadIdx.x;

    float aff[N_EXP];
    const float4* p = (const float4*)(aff_in + (size_t)t * N_EXP);
    #pragma unroll
    for (int q = 0; q < 4; ++q) {
        float4 v = p[q];
        aff[q*4+0] = v.x; aff[q*4+1] = v.y; aff[q*4+2] = v.z; aff[q*4+3] = v.w;
    }
    #pragma unroll
    for (int e = 0; e < N_EXP; ++e) aff[e] += bias[e];

    float m = aff[0];
    #pragma unroll
    for (int e = 1; e < N_EXP; ++e) m = fmaxf(m, aff[e]);
    float s = 0.f;
    #pragma unroll
    for (int e = 0; e < N_EXP; ++e) s += __expf(aff[e] - m);

    float4* pr = (float4*)(probs + (size_t)t * N_EXP);
    #pragma unroll
    for (int q = 0; q < 4; ++q) {
        float4 v;
        v.x = __expf(aff[q*4+0] - m) / s;
        v.y = __expf(aff[q*4+1] - m) / s;
        v.z = __expf(aff[q*4+2] - m) / s;
        v.w = __expf(aff[q*4+3] - m) / s;
        pr[q] = v;
    }

    unsigned long long key[N_EXP];
    #pragma unroll
    for (int j = 0; j < N_EXP; ++j)
        key[j] = ((unsigned long long)f2ord(aff[j]) << 4) | (unsigned long long)(15 - j);
    unsigned long long pk = 0ull;
    unsigned int used = 0;
    for (int r = 0; r < N_EXP; ++r) {
        unsigned long long bk = 0ull; int be = 0;
        for (int j = 0; j < N_EXP; ++j)
            if (!((used >> j) & 1u) && key[j] > bk) { bk = key[j]; be = j; }
        used |= (1u << be);
        pk = (pk << 4) | (unsigned long long)be;
    }
    pref[t] = pk;
}

// ---------------- Kernel 3: fill-event schedule via segment bitmasks (1 block) ----------------
__global__ __launch_bounds__(512) void events_kernel(
    const unsigned long long* __restrict__ pref, int* __restrict__ evt)
{
    __shared__ unsigned long long prefL[T_TOK];            // 64 KB
    __shared__ unsigned long long segmask[N_EXP][NSEG + 1];// 16.5 KB, [e][s]
    __shared__ int pseg[N_EXP][NSEG + 1];
    __shared__ int rem_cap[N_EXP], fparr[N_EXP];
    __shared__ int s_avail, s_pmin, s_fe, s_seglo;
    __shared__ int evp[N_EXP], evf[N_EXP];

    const int tid  = threadIdx.x;
    const int wave = tid >> 6, lane = tid & 63;
    const unsigned long long lt_mask = (1ull << lane) - 1ull;

    for (int i = tid; i < T_TOK; i += 512) prefL[i] = pref[i];
    if (tid < N_EXP) rem_cap[tid] = CAP;
    if (tid == 0) { s_avail = 0xFFFF; s_seglo = 0; }
    __syncthreads();

    // initial masks from top-nibble choice
    for (int s = wave; s < NSEG; s += 8) {
        int c = (int)(prefL[s * 64 + lane] >> 60);
        #pragma unroll
        for (int e = 0; e < N_EXP; ++e) {
            unsigned long long mm = __ballot(c == e);
            if (lane == e) segmask[e][s] = mm;
        }
    }
    __syncthreads();

    for (int round = 0; round < N_EXP; ++round) {
        const unsigned int avail = (unsigned int)s_avail;

        // A: counts from popc, prefix scan, crossing locate (wave owns e=wave, wave+8)
        #pragma unroll
        for (int ee = 0; ee < 2; ++ee) {
            const int e = wave + ee * 8;
            const unsigned long long m0 = segmask[e][lane];
            const unsigned long long m1 = segmask[e][64 + lane];
            const int c0 = (int)__popcll(m0), c1 = (int)__popcll(m1);
            int v0 = c0;
            #pragma unroll
            for (int d = 1; d < 64; d <<= 1) {
                int o = __shfl_up(v0, d, 64);
                if (lane >= d) v0 += o;
            }
            const int excl0 = v0 - c0;
            const int tot0  = __shfl(v0, 63, 64);
            int v1 = c1;
            #pragma unroll
            for (int d = 1; d < 64; d <<= 1) {
                int o = __shfl_up(v1, d, 64);
                if (lane >= d) v1 += o;
            }
            const int excl1 = tot0 + v1 - c1;
            pseg[e][lane]      = excl0;
            pseg[e][64 + lane] = excl1;

            int fp = 0x7FFFFFFF;
            if ((avail >> e) & 1u) {
                const int need = rem_cap[e];
                int segc = -1, kk = 0;
                if (excl0 < need && excl0 + c0 >= need)      { segc = lane;      kk = need - excl0; }
                else if (excl1 < need && excl1 + c1 >= need) { segc = 64 + lane; kk = need - excl1; }
                unsigned long long b = __ballot(segc >= 0);
                if (b) {
                    int l2    = __builtin_ctzll(b);
                    int sstar = __shfl(segc, l2, 64);
                    int k2    = __shfl(kk,   l2, 64);
                    unsigned long long m = segmask[e][sstar];
                    int rr = (int)__popcll(m & lt_mask);
                    bool hit = ((m >> lane) & 1ull) && (rr == k2 - 1);
                    unsigned long long hb = __ballot(hit);
                    fp = sstar * 64 + __builtin_ctzll(hb);
                }
            }
            if (lane == 0) fparr[e] = fp;
        }
        __syncthreads();

        // B: earliest fill event
        if (tid == 0) {
            int pm = 0x7FFFFFFF, f = 0;
            #pragma unroll
            for (int e = 0; e < N_EXP; ++e)
                if (fparr[e] < pm) { pm = fparr[e]; f = e; }
            s_pmin = pm; s_fe = f;
        }
        __syncthreads();
        const int pmin = s_pmin, fe = s_fe;
        const int segF = pmin >> 6;
        const int seglo = s_seglo;

        // C: capacity update + prune finalized bits
        if (tid < N_EXP) {
            const int e = tid;
            unsigned long long mlep = ((pmin & 63) == 63) ? ~0ull
                                      : ((1ull << ((pmin & 63) + 1)) - 1ull);
            unsigned long long m = segmask[e][segF];
            rem_cap[e] -= pseg[e][segF] + (int)__popcll(m & mlep);
            segmask[e][segF] = m & ~mlep;
        }
        for (int i = tid; i < (segF - seglo) * N_EXP; i += 512)
            segmask[i & 15][seglo + (i >> 4)] = 0ull;
        if (tid == 0) {
            evp[round] = pmin; evf[round] = fe;
            s_avail = (int)(avail & ~(1u << fe));
            s_seglo = segF;
        }
        __syncthreads();

        // D: rewalk only tokens whose choice was fe (set bits of segmask[fe][*])
        if (round < N_EXP - 1) {
            const unsigned int navail = avail & ~(1u << fe);
            for (int s = segF + wave; s < NSEG; s += 8) {
                unsigned long long m = segmask[fe][s];
                if (m) {
                    if ((m >> lane) & 1ull) {
                        unsigned long long pp = prefL[s * 64 + lane];
                        int e2 = (int)(pp >> 60);
                        while (!((navail >> e2) & 1u)) { pp <<= 4; e2 = (int)(pp >> 60); }
                        atomicOr(&segmask[e2][s], 1ull << lane);
                    }
                    if (lane == 0) segmask[fe][s] = 0ull;
                }
            }
        }
        __syncthreads();
    }

    if (tid < N_EXP) { evt[tid] = evp[tid]; evt[N_EXP + tid] = evf[tid]; }
}

// ---------------- Kernel 4: final choice per token + per-block expert counts ----------------
__global__ __launch_bounds__(256) void choice_kernel(
    const unsigned long long* __restrict__ pref, const int* __restrict__ evt,
    unsigned char* __restrict__ t2e, int* __restrict__ bcnt)
{
    __shared__ int evp[N_EXP], evf[N_EXP];
    __shared__ int sc[4][N_EXP];
    const int tid = threadIdx.x, b = blockIdx.x;
    const int wave = tid >> 6, lane = tid & 63;
    if (tid < N_EXP) evp[tid] = evt[tid];
    else if (tid < 2 * N_EXP) evf[tid - N_EXP] = evt[tid];
    __syncthreads();

    const int t = b * 256 + tid;
    unsigned int mask = 0xFFFFu;
    #pragma unroll
    for (int j = 0; j < N_EXP; ++j)
        if (evp[j] < t) mask &= ~(1u << evf[j]);

    unsigned long long pp = pref[t];
    int e = (int)(pp >> 60);
    while (!((mask >> e) & 1u)) { pp <<= 4; e = (int)(pp >> 60); }
    t2e[t] = (unsigned char)e;

    #pragma unroll
    for (int e2 = 0; e2 < N_EXP; ++e2) {
        unsigned long long mm = __ballot(e == e2);
        if (lane == e2) sc[wave][e2] = (int)__popcll(mm);
    }
    __syncthreads();
    if (tid < N_EXP)
        bcnt[b * N_EXP + tid] = sc[0][tid] + sc[1][tid] + sc[2][tid] + sc[3][tid];
}

// ---------------- Kernel 5: ranks + write out0/out1 ----------------
__global__ __launch_bounds__(256) void writeout_kernel(
    const unsigned char* __restrict__ t2e, const int* __restrict__ bcnt,
    const float* __restrict__ probs,
    float* __restrict__ out0, float* __restrict__ out1)
{
    __shared__ int base[N_EXP];
    __shared__ int sc[4][N_EXP];
    const int tid = threadIdx.x, b = blockIdx.x;
    const int wave = tid >> 6, lane = tid & 63;
    const unsigned long long lt_mask = (1ull << lane) - 1ull;

    const int t = b * 256 + tid;
    const int c = (int)t2e[t];

    unsigned long long own = 0ull;
    #pragma unroll
    for (int e2 = 0; e2 < N_EXP; ++e2) {
        unsigned long long mm = __ballot(c == e2);
        if (c == e2) own = mm;
        if (lane == e2) sc[wave][e2] = (int)__popcll(mm);
    }
    if (tid < N_EXP) {
        int s = 0;
        for (int b2 = 0; b2 < b; ++b2) s += bcnt[b2 * N_EXP + tid];
        base[tid] = s;
    }
    __syncthreads();

    int rank = (int)__popcll(own & lt_mask);
    for (int w2 = 0; w2 < wave; ++w2) rank += sc[w2][c];
    const int pos = base[c] + rank;
    out0[c * CAP + pos] = (float)t;
    out1[t] = probs[(size_t)t * N_EXP + c];
}

extern "C" void kernel_launch(void* const* d_in, const int* in_sizes, int n_in,
                              void* d_out, int out_size, void* d_ws, size_t ws_size,
                              hipStream_t stream) {
    const float* feat = (const float*)d_in[0];
    const float* W    = (const float*)d_in[1];
    const float* bias = (const float*)d_in[2];

    float* out = (float*)d_out;
    char*  ws  = (char*)d_ws;

    float* aff               = (float*)ws;
    unsigned long long* pref = (unsigned long long*)(ws + 524288);
    float* probs             = (float*)(ws + 589824);
    int* evt                 = (int*)(ws + 1114112);
    unsigned char* t2e       = (unsigned char*)(ws + 1114240);
    int* bcnt                = (int*)(ws + 1122432);

    hipLaunchKernelGGL(gemm_aff_kernel, dim3(512), dim3(256), 0, stream,
                       feat, W, aff);
    hipLaunchKernelGGL(finalize_kernel, dim3(T_TOK / 256), dim3(256), 0, stream,
                       aff, bias, pref, probs);
    hipLaunchKernelGGL(events_kernel, dim3(1), dim3(512), 0, stream,
                       pref, evt);
    hipLaunchKernelGGL(choice_kernel, dim3(T_TOK / 256), dim3(256), 0, stream,
                       pref, evt, t2e, bcnt);
    hipLaunchKernelGGL(writeout_kernel, dim3(T_TOK / 256), dim3(256), 0, stream,
                       t2e, bcnt, probs, out, out + T_TOK);
}